// Round 3
// baseline (75.952 us; speedup 1.0000x reference)
//
#include <hip/hip_runtime.h>
#include <math.h>

// Problem constants (setup_inputs is fixed: B=64, T=512, H=768, L=400)
namespace {
constexpr int kB  = 64;
constexpr int kT  = 512;
constexpr int kH  = 768;
constexpr int kHm = 767;       // H-1 feature channels
constexpr int kL  = 400;       // max_label_length
constexpr int kC  = 16;        // k-chunks (parallel scan segments)
constexpr int kTC = kL / kC;   // 25: target chunk boundary spacing
constexpr int kBK = 32;        // per-batch register buffer depth
constexpr int kLwPad = kL + kBK; // LDS coeff array padded so unconditional
                                 // lw[k0+i] reads stay in-bounds
}

__device__ __forceinline__ float sigmoidf_(float x) {
  return 1.0f / (1.0f + expf(-x));
}

// One block per batch element b (512 threads):
//  - sigmoid of alpha channel for all T steps (parallel) + block-reduce sum
//  - lane 0 runs the 400-step scalar recurrence, emitting (w, m, sel) per k
//    (out_k = s + w*x ; s_new = sel*s + m*x) and, per chunk c, the rebuild
//    start index start_c = (last fire < 25*c) + 1  (0 if none).
__global__ __launch_bounds__(512) void k_rec(
    const float* __restrict__ hs, const int* __restrict__ labels,
    float* __restrict__ asum_ws, int* __restrict__ starts_ws,
    float4* __restrict__ wms) {
  __shared__ float a_lds[kT];
  __shared__ float red[kT];
  const int b = blockIdx.x;
  const int tid = threadIdx.x;

  float sig = sigmoidf_(hs[(size_t)b * kT * kH + (size_t)tid * kH + kHm]);
  a_lds[tid] = sig;
  red[tid] = sig;
  __syncthreads();
  for (int off = 256; off > 0; off >>= 1) {
    if (tid < off) red[tid] += red[tid + off];
    __syncthreads();
  }

  if (tid == 0) {
    const float as = red[0];
    asum_ws[b] = as;
    const int lab = labels[b];
    const float len = (float)(lab < kL ? lab : kL);
    const float scale = len / as;
    float a_r = 0.0f;
    int last_fire = -1;
    float4* wb = wms + b * kL;
    int* sb = starts_ws + b * (kC + 1);
    for (int c = 0; c < kC; ++c) {
      sb[c] = last_fire + 1;  // state entering 25*c rebuilds from here
      const int kbase = c * kTC;
#pragma unroll
      for (int kk = 0; kk < kTC; ++kk) {
        const int k = kbase + kk;
        const float ak = a_lds[k] * scale;
        const float a_a = ak + a_r;
        const bool fired = (a_a >= 1.0f);
        const float w   = fired ? (1.0f - a_r) : ak;
        const float arn = fired ? (ak - (1.0f - a_r)) : a_a;  // exact ref expr
        const float m   = fired ? arn : ak;
        const float sel = fired ? 0.0f : 1.0f;
        wb[k] = make_float4(w, m, sel, 0.0f);
        if (fired) last_fire = k;
        a_r = arn;
      }
    }
    sb[kC] = kL;
  }
}

// Chunk-parallel scan: grid (3, B, kC). Block (x, b, c) handles h-range
// [256x, 256x+255] of batch b over k in [start_c, start_{c+1}).
// Chunk boundaries sit right after a fire (sel=0 state reset), so the entry
// state is exactly m[start-1] * x[start-1]: one extra read, no prefix scan.
__global__ __launch_bounds__(256) void k_scan(
    const float* __restrict__ hs, const int* __restrict__ labels,
    const float* __restrict__ asum_ws, const int* __restrict__ starts_ws,
    const float4* __restrict__ wms, float* __restrict__ out) {
  __shared__ float4 lw[kLwPad];
  const int b = blockIdx.y;
  const int c = blockIdx.z;
  const int tid = threadIdx.x;

  for (int i = tid; i < kL; i += 256) lw[i] = wms[b * kL + i];
  for (int i = kL + tid; i < kLwPad; i += 256) lw[i] = make_float4(0, 0, 0, 0);

  // n_hat = sum_b (len_b - alpha_sum_b)^2, once, in block (0,0,0)
  if (blockIdx.x == 0 && b == 0 && c == 0 && tid < kB) {
    const float as = asum_ws[tid];
    const int lab = labels[tid];
    const float len = (float)(lab < kL ? lab : kL);
    const float d = len - as;
    float v = d * d;
    for (int off = 32; off > 0; off >>= 1) v += __shfl_down(v, off, 64);
    if (tid == 0) out[(size_t)kB * kL * kHm] = v;
  }
  __syncthreads();

  const int start = __builtin_amdgcn_readfirstlane(starts_ws[b * (kC + 1) + c]);
  const int end   = __builtin_amdgcn_readfirstlane(starts_ws[b * (kC + 1) + c + 1]);
  if (start >= end) return;  // empty chunk (sparse-fire row)

  const int h = blockIdx.x * 256 + tid;
  if (h >= kHm) return;

  const float* __restrict__ px = hs + (size_t)b * kT * kH + h;
  float* __restrict__ po = out + (size_t)b * kL * kHm + h;

  float s = 0.0f;
  if (start > 0) {  // rebuild state from the fire just before the chunk
    const float xj = px[(size_t)(start - 1) * kH];
    s = lw[start - 1].y * xj;  // == m * x, bitwise same as fmaf(m,x,0*s)
  }

  for (int k0 = start; k0 < end; k0 += kBK) {
    float x[kBK];
#pragma unroll
    for (int i = 0; i < kBK; ++i) {
      x[i] = px[(size_t)(k0 + i) * kH];  // k0+i <= 399+31 < T=512: in-bounds
    }
#pragma unroll
    for (int i = 0; i < kBK; ++i) {
      const float4 c4 = lw[k0 + i];
      if (k0 + i < end) {  // scalar-uniform guard
        const float o = fmaf(c4.x, x[i], s);
        po[(size_t)(k0 + i) * kHm] = o;
        s = fmaf(c4.y, x[i], c4.z * s);
      }
    }
  }
}

extern "C" void kernel_launch(void* const* d_in, const int* in_sizes, int n_in,
                              void* d_out, int out_size, void* d_ws, size_t ws_size,
                              hipStream_t stream) {
  const float* hs     = (const float*)d_in[0];
  const int*   labels = (const int*)d_in[1];
  float* out = (float*)d_out;

  // ws layout: [0,256) alpha_sum (64 f32); [256, 4608) starts (64 x 17 i32);
  // [8192, 8192+410KB) (w,m,sel,_) float4 per (b,k).
  float*  asum_ws   = (float*)d_ws;
  int*    starts_ws = (int*)((char*)d_ws + 256);
  float4* wms       = (float4*)((char*)d_ws + 8192);

  k_rec<<<kB, 512, 0, stream>>>(hs, labels, asum_ws, starts_ws, wms);
  k_scan<<<dim3((kHm + 255) / 256, kB, kC), 256, 0, stream>>>(
      hs, labels, asum_ws, starts_ws, wms, out);
}